// Round 5
// baseline (387.161 us; speedup 1.0000x reference)
//
#include <hip/hip_runtime.h>
#include <hip/hip_fp16.h>

// Net_55439437857087: per-pixel MLP 2->8->4x(8x8)->3 over 16.7M pixels.
// History: R3/R4 512x512 table + bilinear (199us main). R5 quad 4MB:
// REGRESSED (L2 thrash + NT-store write amplification at 96B/thread).
// R6 horiz-pair (2 loads/px, 2 lines/px): 192us — halving REQUESTS gained
// only 3.5% -> request-rate theories dead. R7 vertical-pair (2 loads/px,
// 1.14 lines/px): 151us — line-count is the lever (~3.3 cy/CU per line).
// Cost model now: 48us streaming + ~100us line-touch serialization.
// R8 infra-failed (container lost twice, no data). R9 = resubmit of the
// 3-way within-round A/B over pixel thirds, same table:
//   A: control, R7 sampler (2x 8B loads)
//   B: single 16B (8-aligned) gather  -> bounds per-instruction term
//   C: B + nontemporal gather (no L1 allocate) -> tests L1-fill-overhead
//      hypothesis; if nt hurts L2 residency instead, C slows + FETCH jumps.
// All variants bit-identical math -> absmax must stay 0.00390625.

#define EXP2F(x) __builtin_amdgcn_exp2f(x)
#define RCPF(x)  __builtin_amdgcn_rcpf(x)

#define G 512
#define GM1F 511.0f

typedef float vfloat4 __attribute__((ext_vector_type(4)));  // nontemporal-compatible
typedef unsigned int uv4 __attribute__((ext_vector_type(4), aligned(8)));

// ---- shared network evaluation (scale constants folded inline) ----
__device__ __forceinline__ void net_eval(
    float px, float py,
    const float* __restrict__ Win, const float* __restrict__ Wh,
    const float* __restrict__ Wout, float o[3])
{
    const float S  = 2.8853900817779268f;   // 2*log2(e)
    const float SO = -1.4426950408889634f;  // -log2(e)
    float h[8];
#pragma unroll
    for (int j = 0; j < 8; ++j) {
        float acc = __builtin_fmaf(px, Win[2 * j], py * Win[2 * j + 1]);
        h[j] = __builtin_fmaf(-2.0f, RCPF(EXP2F(S * acc) + 1.0f), 1.0f);
    }
#pragma unroll
    for (int L = 0; L < 4; ++L) {
        float nh[8];
#pragma unroll
        for (int j = 0; j < 8; ++j) {
            float acc = 0.0f;
#pragma unroll
            for (int k = 0; k < 8; ++k)
                acc = __builtin_fmaf(h[k], Wh[8 * j + k], acc);
            nh[j] = __builtin_fmaf(-2.0f, RCPF(EXP2F(S * acc) + 1.0f), 1.0f);
        }
#pragma unroll
        for (int j = 0; j < 8; ++j) h[j] = nh[j];
    }
#pragma unroll
    for (int c = 0; c < 3; ++c) {
        float acc = 0.0f;
#pragma unroll
        for (int k = 0; k < 8; ++k)
            acc = __builtin_fmaf(h[k], Wout[8 * c + k], acc);
        o[c] = RCPF(EXP2F(SO * acc) + 1.0f);
    }
}

// ================= build passes (unchanged from R7) =================

__global__ __launch_bounds__(256) void build_tex_kernel(
    const float* __restrict__ Win, const float* __restrict__ Wh,
    const float* __restrict__ Wout, unsigned int* __restrict__ tex)
{
    int t = blockIdx.x * blockDim.x + threadIdx.x;
    if (t >= G * G) return;
    int i = t & (G - 1);
    int j = t >> 9;               // t / G
    const float inv = 1.0f / GM1F;
    float o[3];
    net_eval(i * inv, j * inv, Win, Wh, Wout, o);
    unsigned int r = (unsigned int)__builtin_rintf(o[0] * 2047.0f);
    unsigned int g = (unsigned int)__builtin_rintf(o[1] * 2047.0f);
    unsigned int b = (unsigned int)__builtin_rintf(o[2] * 1023.0f);
    tex[t] = r | (g << 11) | (b << 22);
}

// Entry (ix,iy): texel(ix,iy) in .x, texel(ix,iy+1) in .y  (vertical pair)
__global__ __launch_bounds__(256) void build_vpair_kernel(
    const unsigned int* __restrict__ tex, uint2* __restrict__ pair)
{
    int t = blockIdx.x * blockDim.x + threadIdx.x;
    if (t >= G * G) return;
    int ix = t & (G - 1);
    int iy = t >> 9;
    int iy1 = min(iy + 1, G - 1);
    uint2 q;
    q.x = tex[iy * G + ix];
    q.y = tex[iy1 * G + ix];
    pair[t] = q;
}

// ================= samplers =================

__device__ __forceinline__ float3 unpack_raw(unsigned int v) {
    return make_float3((float)(v & 2047u),
                       (float)((v >> 11) & 2047u),
                       (float)(v >> 22));
}

__device__ __forceinline__ float3 lerp3(float3 a, float3 b, float t) {
    return make_float3(__builtin_fmaf(t, b.x - a.x, a.x),
                       __builtin_fmaf(t, b.y - a.y, a.y),
                       __builtin_fmaf(t, b.z - a.z, a.z));
}

// A: control — two 8B loads (exact R7)
__device__ __forceinline__ float3 sample_vpair(
    const uint2* __restrict__ tab, float px, float py)
{
    float fx = px * GM1F;
    float fy = py * GM1F;
    int ix = (int)fx;             // px in [0,1): ix <= 510, iy <= 510
    int iy = (int)fy;
    float tx = fx - (float)ix;
    float ty = fy - (float)iy;
    const uint2* e = tab + (iy << 9) + ix;
    uint2 e0 = e[0];
    uint2 e1 = e[1];
    float3 c0 = lerp3(unpack_raw(e0.x), unpack_raw(e1.x), tx);
    float3 c1 = lerp3(unpack_raw(e0.y), unpack_raw(e1.y), tx);
    float3 r  = lerp3(c0, c1, ty);
    return make_float3(r.x * (1.0f / 2047.0f),
                       r.y * (1.0f / 2047.0f),
                       r.z * (1.0f / 1023.0f));
}

// B: single 16B (8-aligned) gather
__device__ __forceinline__ float3 sample_vpair16(
    const uint2* __restrict__ tab, float px, float py)
{
    float fx = px * GM1F;
    float fy = py * GM1F;
    int ix = (int)fx;
    int iy = (int)fy;
    float tx = fx - (float)ix;
    float ty = fy - (float)iy;
    uv4 q = *reinterpret_cast<const uv4*>(tab + (iy << 9) + ix);
    // q.x=top(ix) q.y=bot(ix) q.z=top(ix+1) q.w=bot(ix+1)
    float3 c0 = lerp3(unpack_raw(q.x), unpack_raw(q.z), tx);
    float3 c1 = lerp3(unpack_raw(q.y), unpack_raw(q.w), tx);
    float3 r  = lerp3(c0, c1, ty);
    return make_float3(r.x * (1.0f / 2047.0f),
                       r.y * (1.0f / 2047.0f),
                       r.z * (1.0f / 1023.0f));
}

// C: single 16B nontemporal gather (no L1 allocate)
__device__ __forceinline__ float3 sample_vpair16nt(
    const uint2* __restrict__ tab, float px, float py)
{
    float fx = px * GM1F;
    float fy = py * GM1F;
    int ix = (int)fx;
    int iy = (int)fy;
    float tx = fx - (float)ix;
    float ty = fy - (float)iy;
    uv4 q = __builtin_nontemporal_load(
        reinterpret_cast<const uv4*>(tab + (iy << 9) + ix));
    float3 c0 = lerp3(unpack_raw(q.x), unpack_raw(q.z), tx);
    float3 c1 = lerp3(unpack_raw(q.y), unpack_raw(q.w), tx);
    float3 r  = lerp3(c0, c1, ty);
    return make_float3(r.x * (1.0f / 2047.0f),
                       r.y * (1.0f / 2047.0f),
                       r.z * (1.0f / 1023.0f));
}

// ================= main-pass variants (4 px/thread, thread-range slice) ===

#define MAIN_BODY(SAMPLER)                                                 \
    int tid = blockIdx.x * blockDim.x + threadIdx.x;                       \
    if (tid >= tn) return;                                                 \
    int t = t0 + tid;                                                      \
    const vfloat4* xv = reinterpret_cast<const vfloat4*>(x);               \
    vfloat4 xa = __builtin_nontemporal_load(&xv[2 * t + 0]);               \
    vfloat4 xb = __builtin_nontemporal_load(&xv[2 * t + 1]);               \
    float3 o0 = SAMPLER(tab, xa.x, xa.y);                                  \
    float3 o1 = SAMPLER(tab, xa.z, xa.w);                                  \
    float3 o2 = SAMPLER(tab, xb.x, xb.y);                                  \
    float3 o3 = SAMPLER(tab, xb.z, xb.w);                                  \
    vfloat4 s0 = {o0.x, o0.y, o0.z, o1.x};                                 \
    vfloat4 s1 = {o1.y, o1.z, o2.x, o2.y};                                 \
    vfloat4 s2 = {o2.z, o3.x, o3.y, o3.z};                                 \
    vfloat4* op = reinterpret_cast<vfloat4*>(out);                         \
    __builtin_nontemporal_store(s0, &op[3 * t + 0]);                       \
    __builtin_nontemporal_store(s1, &op[3 * t + 1]);                       \
    __builtin_nontemporal_store(s2, &op[3 * t + 2]);

__global__ __launch_bounds__(256) void vpair_a_kernel(
    const float* __restrict__ x, const uint2* __restrict__ tab,
    float* __restrict__ out, int t0, int tn)
{
    MAIN_BODY(sample_vpair)
}

__global__ __launch_bounds__(256) void vpair_b_kernel(
    const float* __restrict__ x, const uint2* __restrict__ tab,
    float* __restrict__ out, int t0, int tn)
{
    MAIN_BODY(sample_vpair16)
}

__global__ __launch_bounds__(256) void vpair_c_kernel(
    const float* __restrict__ x, const uint2* __restrict__ tab,
    float* __restrict__ out, int t0, int tn)
{
    MAIN_BODY(sample_vpair16nt)
}

// ================= fallback: direct evaluation, if ws too small =========

__global__ __launch_bounds__(256) void direct_kernel(
    const float* __restrict__ x,
    const float* __restrict__ Win, const float* __restrict__ Wh,
    const float* __restrict__ Wout, float* __restrict__ out, int npix)
{
    int t = blockIdx.x * blockDim.x + threadIdx.x;
    if (t * 4 >= npix) return;
    const float4* xv = reinterpret_cast<const float4*>(x);
    float4 xa = xv[2 * t + 0];
    float4 xb = xv[2 * t + 1];
    float o[4][3];
    net_eval(xa.x, xa.y, Win, Wh, Wout, o[0]);
    net_eval(xa.z, xa.w, Win, Wh, Wout, o[1]);
    net_eval(xb.x, xb.y, Win, Wh, Wout, o[2]);
    net_eval(xb.z, xb.w, Win, Wh, Wout, o[3]);
    float4 s0 = make_float4(o[0][0], o[0][1], o[0][2], o[1][0]);
    float4 s1 = make_float4(o[1][1], o[1][2], o[2][0], o[2][1]);
    float4 s2 = make_float4(o[2][2], o[3][0], o[3][1], o[3][2]);
    float4* op = reinterpret_cast<float4*>(out);
    op[3 * t + 0] = s0;
    op[3 * t + 1] = s1;
    op[3 * t + 2] = s2;
}

extern "C" void kernel_launch(void* const* d_in, const int* in_sizes, int n_in,
                              void* d_out, int out_size, void* d_ws, size_t ws_size,
                              hipStream_t stream) {
    const float* x    = (const float*)d_in[0];
    const float* Win  = (const float*)d_in[1];
    const float* Wh   = (const float*)d_in[2];
    const float* Wout = (const float*)d_in[3];
    float* out = (float*)d_out;

    const int npix = in_sizes[0] / 2;        // 16,777,216
    const int block = 256;

    const size_t pair_bytes = (size_t)G * G * sizeof(uint2);        // 2 MiB
    const size_t tex_bytes  = (size_t)G * G * sizeof(unsigned int); // 1 MiB

    if (ws_size >= pair_bytes + tex_bytes) {
        uint2* pair = (uint2*)d_ws;
        unsigned int* tex = (unsigned int*)((char*)d_ws + pair_bytes);
        build_tex_kernel<<<(G * G) / block, block, 0, stream>>>(Win, Wh, Wout, tex);
        build_vpair_kernel<<<(G * G) / block, block, 0, stream>>>(tex, pair);

        // 3-way slice: thirds of the thread range, block-aligned
        const int T = npix / 4;                       // total threads (4 px each)
        int T1 = ((T / 3) / block) * block;           // slice A
        int T2 = T1;                                  // slice B
        int T3 = T - T1 - T2;                         // slice C (remainder)
        vpair_a_kernel<<<T1 / block, block, 0, stream>>>(x, pair, out, 0, T1);
        vpair_b_kernel<<<T2 / block, block, 0, stream>>>(x, pair, out, T1, T2);
        vpair_c_kernel<<<(T3 + block - 1) / block, block, 0, stream>>>(
            x, pair, out, T1 + T2, T3);
    } else {
        const int nthreads = npix / 4;
        direct_kernel<<<(nthreads + block - 1) / block, block, 0, stream>>>(
            x, Win, Wh, Wout, out, npix);
    }
}